// Round 13
// baseline (122.630 us; speedup 1.0000x reference)
//
#include <hip/hip_runtime.h>

// ImageLRU as one GEMM: y[r,:] = W @ x[r,:], W (1024x1024, block-lower-tri)
// built on device. R13: persistent-A-slab GEMM.
//   Diagnosis R7-R12: all ~120us variants moved ~600 MB of A re-reads through
//   L3 (8 logical reads of X, one per 128-col N-tile). Fix: one block owns a
//   64-row slab for ALL 1024 output cols; X read ONCE (coalesced fp32),
//   converted in-register, kept in LDS (136 KB, padded stride: writes 2-way,
//   frag reads 2-way = free). No barriers after the prologue (LDS read-only).
//   W-fragments register-direct from L2-resident tiled Wh (R8/9-proven),
//   depth-4 named prefetch. Per-block work identical -> zero imbalance.
//   1-term precision: y = bf16(X)*bf16(W) (absmax 8192, thr 32768).

namespace {

typedef __attribute__((ext_vector_type(8))) short short8v;
typedef __attribute__((ext_vector_type(4))) float f32x4;

__device__ inline unsigned short f2bf_rne(float f) {
    unsigned u = __builtin_bit_cast(unsigned, f);
    u += 0x7fffu + ((u >> 16) & 1u);
    return (unsigned short)(u >> 16);
}

// W tiled layout ([128 n][32 k] per 4096-ushort tile): elem (row,k) at
//   tile_base + ((k>>3)<<10) + (row<<3) + (k&7)
// A LDS layout: k-group kg=k>>3 (0..127) stride 544 ushorts, + row*8 + (k&7).
//   544 = 512 + 32 pad: write bank-step (1088B>>2)&31 = 16 -> 2-way (free);
//   frag-read rows 0..15 at fixed kg -> banks row*4&31 -> 2-way (free).

// ---------------- prep: build Wh (bf16) in tiled layout ----------------
__global__ __launch_bounds__(256) void build_w_kernel(
    const float* __restrict__ Lre, const float* __restrict__ Lim,
    const float* __restrict__ Bre, const float* __restrict__ Bim,
    const float* __restrict__ Cre, const float* __restrict__ Cim,
    const float* __restrict__ Dm,
    unsigned short* __restrict__ Wh)
{
    const int i = blockIdx.x >> 6, j = blockIdx.x & 63;
    const int t = threadIdx.x, k = t >> 4, l = t & 15;

    const int n_g = i * 16 + k;        // W row (n dim)
    const int k_g = j * 16 + l;        // W col (k dim)
    const size_t widx = (((size_t)((n_g >> 7) * 32 + (k_g >> 5))) << 12)
                      + (((k_g >> 3) & 3) << 10) + ((n_g & 127) << 3) + (k_g & 7);

    if (j > i) { Wh[widx] = 0; return; }

    __shared__ float2 Bs[16][16];
    __shared__ float2 M[16][16];
    Bs[k][l] = make_float2(Bre[t], Bim[t]);
    M[k][l]  = make_float2(k == l ? 1.f : 0.f, 0.f);
    const int delta = i - j;
    __syncthreads();

    #pragma unroll
    for (int d = 0; d < 6; ++d) {
        const int s = 1 << d;
        if (delta & s) {
            const float lr = Lre[k], li = Lim[k];
            const float2 m0 = M[k][l];
            M[k][l] = make_float2(lr * m0.x - li * m0.y, lr * m0.y + li * m0.x);
            __syncthreads();
        } else if (j + (delta & (s - 1)) >= s) {
            float2 acc = make_float2(0.f, 0.f);
            #pragma unroll
            for (int m = 0; m < 16; ++m) {
                const float2 b = Bs[k][m], v = M[m][l];
                acc.x += b.x * v.x - b.y * v.y;
                acc.y += b.x * v.y + b.y * v.x;
            }
            __syncthreads();
            M[k][l] = acc;
            __syncthreads();
        }
    }

    float w = 0.f;
    #pragma unroll
    for (int m = 0; m < 16; ++m) {
        const float2 v = M[m][l];
        w += Cre[k * 16 + m] * v.x - Cim[k * 16 + m] * v.y;
    }
    if (i == j) w += Dm[t];
    Wh[widx] = f2bf_rne(w);
}

// -------- main GEMM: persistent 64-row A slab, all 1024 cols per block ------
__global__ __launch_bounds__(512) void gemm_persist_kernel(
    const float* __restrict__ X,
    const unsigned short* __restrict__ Wh,
    float* __restrict__ Y)
{
    __shared__ alignas(16) unsigned short sA[128 * 544];  // 136 KB

    const int blk = blockIdx.x;        // 64-row slab
    const int t = threadIdx.x;
    const int lane = t & 63;
    const int w = t >> 6;              // 8 waves: 2M x 4N
    const int wr = w >> 2;             // row half (32 rows)
    const int wcn = w & 3;             // col quarter (32 of 128)
    const int l15 = lane & 15, lg = lane >> 4;

    // ---- prologue: X slab (64x1024 fp32) -> bf16 LDS, read ONCE ----
    {
        const float* xb = X + (size_t)blk * 65536;
        #pragma unroll 4
        for (int p = 0; p < 16; ++p) {
            const int s = (p << 9) + t;
            const int row = s >> 7, kg = s & 127;   // consecutive t: same row,
            const float* src = xb + (row << 10) + (kg << 3);  // consecutive kg
            const float4 a = *reinterpret_cast<const float4*>(src);
            const float4 b = *reinterpret_cast<const float4*>(src + 4);
            short8v hv;
            hv[0] = (short)f2bf_rne(a.x); hv[1] = (short)f2bf_rne(a.y);
            hv[2] = (short)f2bf_rne(a.z); hv[3] = (short)f2bf_rne(a.w);
            hv[4] = (short)f2bf_rne(b.x); hv[5] = (short)f2bf_rne(b.y);
            hv[6] = (short)f2bf_rne(b.z); hv[7] = (short)f2bf_rne(b.w);
            *reinterpret_cast<short8v*>(sA + kg * 544 + (row << 3)) = hv;
        }
    }
    __syncthreads();                   // only barrier; sA read-only below

    // A-frag LDS base offsets (ushorts), excluding kc term (+= kc*2176)
    int aof[2];
    #pragma unroll
    for (int mm = 0; mm < 2; ++mm) {
        const int row = wr * 32 + mm * 16 + l15;
        aof[mm] = lg * 544 + (row << 3);
    }
    // W-frag offsets within a K-chunk tile
    int wfo[2];
    #pragma unroll
    for (int nn = 0; nn < 2; ++nn)
        wfo[nn] = (lg << 10) + ((wcn * 32 + nn * 16 + l15) << 3);

    for (int nb = 0; nb < 8; ++nb) {
        const int nk = (nb + 1) * 4;   // triangular K-limit, multiple of 4
        f32x4 acc[2][2] = {};

        short8v b0[2], b1[2], b2[2], b3[2];
        const unsigned short* wt = Wh + (((size_t)nb * 32) << 12);
        auto LW = [&](short8v* bb, int kc) {
            const unsigned short* p = wt + ((size_t)kc << 12);
            bb[0] = *reinterpret_cast<const short8v*>(p + wfo[0]);
            bb[1] = *reinterpret_cast<const short8v*>(p + wfo[1]);
        };
        auto MF = [&](const short8v* bb, int kc) {
            short8v ah[2];
            #pragma unroll
            for (int mm = 0; mm < 2; ++mm)
                ah[mm] = *reinterpret_cast<const short8v*>(sA + aof[mm] + kc * 2176);
            #pragma unroll
            for (int mm = 0; mm < 2; ++mm)
                #pragma unroll
                for (int nn = 0; nn < 2; ++nn)
                    acc[mm][nn] = __builtin_amdgcn_mfma_f32_16x16x32_bf16(
                        ah[mm], bb[nn], acc[mm][nn], 0, 0, 0);
        };

        LW(b0, 0); LW(b1, 1); LW(b2, 2); LW(b3, 3);   // depth-4 prefetch
        for (int kc = 0; kc < nk; kc += 4) {
            MF(b0, kc);
            if (kc + 4 < nk) LW(b0, kc + 4);
            MF(b1, kc + 1);
            if (kc + 5 < nk) LW(b1, kc + 5);
            MF(b2, kc + 2);
            if (kc + 6 < nk) LW(b2, kc + 6);
            MF(b3, kc + 3);
            if (kc + 7 < nk) LW(b3, kc + 7);
        }

        // ---- epilogue for this nb: C/D layout col=lane&15, row=(lane>>4)*4+q
        #pragma unroll
        for (int mm = 0; mm < 2; ++mm) {
            const int grow = blk * 64 + wr * 32 + mm * 16 + lg * 4;
            #pragma unroll
            for (int nn = 0; nn < 2; ++nn) {
                const int gcol = nb * 128 + wcn * 32 + nn * 16 + l15;
                #pragma unroll
                for (int q = 0; q < 4; ++q)
                    Y[(size_t)(grow + q) * 1024 + gcol] = acc[mm][nn][q];
            }
        }
    }
}

} // namespace

extern "C" void kernel_launch(void* const* d_in, const int* in_sizes, int n_in,
                              void* d_out, int out_size, void* d_ws, size_t ws_size,
                              hipStream_t stream) {
    const float* x   = (const float*)d_in[0];
    const float* Lre = (const float*)d_in[1];
    const float* Lim = (const float*)d_in[2];
    const float* Bre = (const float*)d_in[3];
    const float* Bim = (const float*)d_in[4];
    const float* Cre = (const float*)d_in[5];
    const float* Cim = (const float*)d_in[6];
    const float* Dm  = (const float*)d_in[7];
    float* y = (float*)d_out;

    const int positions = in_sizes[0] / 1024;          // 32768
    const int slabs = positions / 64;                  // 512

    unsigned short* Wh = (unsigned short*)d_ws;        // 2 MB

    build_w_kernel<<<64 * 64, 256, 0, stream>>>(Lre, Lim, Bre, Bim, Cre, Cim, Dm, Wh);
    gemm_persist_kernel<<<slabs, 512, 0, stream>>>(x, Wh, y);
}